// Round 12
// baseline (695.873 us; speedup 1.0000x reference)
//
#include <hip/hip_runtime.h>

#define N_NODES   100000
#define N_EDGES   800000
#define N_ETYPES  5
#define IN_DIM    23
#define FPAD      32                    // feat dims padded to 32 (64 B bf16 rows)
#define HID_DIM   128
#define OUT_DIM   64
#define NUM_GRAPHS 64
#define NBKT      391                   // ceil(100000/256) buckets of 256 nodes
#define PBLK      125                   // partition blocks per etype
#define CHUNK     6400                  // dst-partition: 125*6400 = 800000
#define VEDGES    900000                // src-partition: 800k edges + 100k self-loops
#define CHUNK2    7200                  // 125*7200 = 900000
#define PN        (N_ETYPES*NBKT*PBLK)  // 244,375 per partition
#define PN2TOT    (2*PN)                // 488,750 (dst + src halves, scanned together)
#define SCAN_NBLK ((PN2TOT + 1023) / 1024)  // 478
#define TOT_EDGES (N_ETYPES*N_EDGES)    // 4,000,000 (dst records)
#define TOT2      (TOT_EDGES + N_ETYPES*VEDGES)  // 8,500,000 (end of src records)
#define BKT_CAP   3072                  // max records per (etype,bucket) segment
#define A1STR     40                    // gemm1 LDS stride: 2-way only (free)

// NOTE (measured r3): bulk LDS float atomics ~3.5 cyc/lane on gfx950 — register acc only.
// NOTE (measured r6): unpadded bf16 LDS tiles -> 16-way conflicts on MFMA ds_read_b128.
// NOTE (measured r7-r11): random row-gather over a table >4MB/XCD has a compulsory
// L2-miss floor of 8 XCDs x table bytes (~256 MB here); occupancy/width tuning cannot
// reduce it. r12: layer-2 gather ELIMINATED via pool-commute: GSUM[g]=Σ_e(C_e[g]·H1)@W2_e
// — src-bucketed spool reads H1 through an L2-hot 256 KB window instead.

__device__ __forceinline__ unsigned short f2bf(float x) {
    unsigned u = __float_as_uint(x);
    unsigned r = (u + 0x7FFFu + ((u >> 16) & 1u)) >> 16;   // RNE
    return (unsigned short)r;
}
__device__ __forceinline__ float bf2f(unsigned short h) {
    return __uint_as_float(((unsigned)h) << 16);
}

typedef __attribute__((ext_vector_type(8))) short bf16x8;
typedef __attribute__((ext_vector_type(4))) float f32x4;

// ---------------- feat -> bf16 table, padded to 32 dims ----------------
__global__ __launch_bounds__(256) void cvt_feat_k(const float* __restrict__ feat,
                                                  unsigned short* __restrict__ fb32) {
    int i = blockIdx.x * 256 + threadIdx.x;
    if (i < N_NODES * FPAD) {
        int n = i >> 5, d = i & 31;
        fb32[i] = (d < IN_DIM) ? f2bf(feat[n * IN_DIM + d]) : (unsigned short)0;
    }
}

// ---------------- weight prep: W1^T bf16 (k-pad 32), b1 sum ----------------
__global__ __launch_bounds__(256) void cvt_w_k(const float* __restrict__ W1,
                                               const float* __restrict__ b1,
                                               unsigned short* __restrict__ w1tb,
                                               float* __restrict__ b1s) {
    int i = blockIdx.x * 256 + threadIdx.x;
    if (i < N_ETYPES * HID_DIM * 32) {
        int e = i / (HID_DIM * 32);
        int r = i - e * (HID_DIM * 32);
        int n = r >> 5, k = r & 31;
        w1tb[i] = (k < IN_DIM) ? f2bf(W1[e * IN_DIM * HID_DIM + k * HID_DIM + n])
                               : (unsigned short)0;
    }
    if (i < HID_DIM) {
        float s = 0.f;
        for (int e = 0; e < N_ETYPES; e++) s += b1[e * HID_DIM + i];
        b1s[i] = s;
    }
}

// ---------------- partition pass 1: dst-hist AND src-hist in one pass ----------
__global__ __launch_bounds__(256) void part1_k(const int* __restrict__ src,
                                               const int* __restrict__ dst,
                                               int* __restrict__ hp) {
    __shared__ int hd[NBKT];
    __shared__ int hs[NBKT];
    int e = blockIdx.y, blk = blockIdx.x, t = threadIdx.x;
    for (int b = t; b < NBKT; b += 256) { hd[b] = 0; hs[b] = 0; }
    __syncthreads();
    const int* dp = dst + e * N_EDGES + blk * CHUNK;
    for (int k = t; k < CHUNK; k += 256) atomicAdd(&hd[dp[k] >> 8], 1);
    const int* sp = src + e * N_EDGES;
    for (int k = t; k < CHUNK2; k += 256) {
        int i = blk * CHUNK2 + k;
        int s = (i < N_EDGES) ? sp[i] : (i - N_EDGES);   // virtual self-loop edges
        atomicAdd(&hs[s >> 8], 1);
    }
    __syncthreads();
    for (int b = t; b < NBKT; b += 256) {
        hp[(e * NBKT + b) * PBLK + blk] = hd[b];
        hp[PN + (e * NBKT + b) * PBLK + blk] = hs[b];
    }
}

// ---------------- exclusive scan over 488,750 ----------------
__global__ __launch_bounds__(256) void scan1_k(const int* __restrict__ in,
                                               int* __restrict__ out,
                                               int* __restrict__ bsum) {
    __shared__ int ls[256];
    int t = threadIdx.x;
    int base = blockIdx.x * 1024 + t * 4;
    int v[4]; int s = 0;
    for (int j = 0; j < 4; j++) { int i = base + j; v[j] = (i < PN2TOT) ? in[i] : 0; s += v[j]; }
    ls[t] = s; __syncthreads();
    for (int o = 1; o < 256; o <<= 1) {
        int x = (t >= o) ? ls[t - o] : 0;
        __syncthreads();
        ls[t] += x;
        __syncthreads();
    }
    int run = (t > 0) ? ls[t - 1] : 0;
    if (t == 255) bsum[blockIdx.x] = ls[255];
    for (int j = 0; j < 4; j++) { int i = base + j; if (i < PN2TOT) out[i] = run; run += v[j]; }
}

__global__ __launch_bounds__(512) void scan2_k(int* __restrict__ bsum) {
    __shared__ int ls[512];
    int t = threadIdx.x;
    int v = (t < SCAN_NBLK) ? bsum[t] : 0;
    ls[t] = v; __syncthreads();
    for (int o = 1; o < 512; o <<= 1) {
        int x = (t >= o) ? ls[t - o] : 0;
        __syncthreads();
        ls[t] += x;
        __syncthreads();
    }
    if (t < SCAN_NBLK) bsum[t] = (t > 0) ? ls[t - 1] : 0;
}

__global__ __launch_bounds__(256) void scan3_k(int* __restrict__ off,
                                               const int* __restrict__ bsum) {
    int i = blockIdx.x * 256 + threadIdx.x;
    if (i < PN2TOT) off[i] += bsum[i >> 10];
}

// ---------------- partition pass 2 (dst records, for layer-1 CSR) ----------------
__global__ __launch_bounds__(256) void part2_k(const int* __restrict__ src,
                                               const int* __restrict__ dst,
                                               const int* __restrict__ off,
                                               unsigned* __restrict__ ep) {
    __shared__ int cur[NBKT];
    int e = blockIdx.y, blk = blockIdx.x, t = threadIdx.x;
    for (int b = t; b < NBKT; b += 256) cur[b] = off[(e * NBKT + b) * PBLK + blk];
    __syncthreads();
    const int* dp = dst + e * N_EDGES + blk * CHUNK;
    const int* sp = src + e * N_EDGES + blk * CHUNK;
    for (int k = t; k < CHUNK; k += 256) {
        int d = dp[k], s = sp[k];
        int b = d >> 8;
        int pos = atomicAdd(&cur[b], 1);
        ep[pos] = (unsigned)s | ((unsigned)(d & 255) << 24);
    }
}

// ---------------- per-bucket counting sort -> node-sorted CSR + NOFF/DEG/INV ---
__global__ __launch_bounds__(256) void sort_k(const int* __restrict__ off,
                                              const unsigned* __restrict__ ep,
                                              unsigned* __restrict__ csr,
                                              int* __restrict__ noff,
                                              int* __restrict__ degn,
                                              float* __restrict__ inv) {
    __shared__ unsigned recs[BKT_CAP];
    __shared__ int hist[256];
    __shared__ int scn[256];
    __shared__ int curp[256];
    int b = blockIdx.x, e = blockIdx.y, t = threadIdx.x;
    int lin = (e * NBKT + b) * PBLK;
    int S = off[lin];
    int E = off[lin + PBLK];             // valid: off[PN] = TOT_EDGES (src half start)
    int cnt = E - S;
    hist[t] = 0;
    __syncthreads();
    for (int i = t; i < cnt; i += 256) {
        unsigned r = ep[S + i];
        recs[i] = r;
        atomicAdd(&hist[r >> 24], 1);
    }
    __syncthreads();
    scn[t] = hist[t];
    __syncthreads();
    for (int o = 1; o < 256; o <<= 1) {
        int x = (t >= o) ? scn[t - o] : 0;
        __syncthreads();
        scn[t] += x;
        __syncthreads();
    }
    int excl = scn[t] - hist[t];
    curp[t] = excl;
    int n = b * 256 + t;
    if (n < N_NODES) {
        noff[e * N_NODES + n] = S + excl;
        degn[e * N_NODES + n] = hist[t];
        inv[e * N_NODES + n]  = 1.f / (float)(hist[t] + 1);
    }
    __syncthreads();
    for (int i = t; i < cnt; i += 256) {
        unsigned r = recs[i];
        int pos = atomicAdd(&curp[r >> 24], 1);
        csr[S + pos] = r & 0xFFFFFFu;
    }
}

// ---------------- partition pass 2b (src records for spool; needs INV) ----------
// record = (src_local<<24) | (gid(dst)<<16) | bf16(inv_e[dst]); self-loops virtual.
__global__ __launch_bounds__(256) void part2b_k(const int* __restrict__ src,
                                                const int* __restrict__ dst,
                                                const int* __restrict__ gid,
                                                const float* __restrict__ inv,
                                                const int* __restrict__ off,
                                                unsigned* __restrict__ ep) {
    __shared__ int cur[NBKT];
    int e = blockIdx.y, blk = blockIdx.x, t = threadIdx.x;
    for (int b = t; b < NBKT; b += 256) cur[b] = off[PN + (e * NBKT + b) * PBLK + blk];
    __syncthreads();
    const int* sp = src + e * N_EDGES;
    const int* dp = dst + e * N_EDGES;
    for (int k = t; k < CHUNK2; k += 256) {
        int i = blk * CHUNK2 + k;
        int s, d;
        if (i < N_EDGES) { s = sp[i]; d = dp[i]; }
        else             { s = i - N_EDGES; d = s; }
        unsigned g = (unsigned)gid[d];
        unsigned wv = f2bf(inv[e * N_NODES + d]);
        int b = s >> 8;
        int pos = atomicAdd(&cur[b], 1);
        ep[pos] = ((unsigned)(s & 255) << 24) | (g << 16) | wv;
    }
}

// ---------------- layer1 pull-aggregate (self-term folded in, bf16 out) --------
__global__ __launch_bounds__(256) void agg1_k(const int* __restrict__ noff,
                                              const int* __restrict__ degn,
                                              const unsigned* __restrict__ csr,
                                              const unsigned short* __restrict__ fb32,
                                              const float* __restrict__ inv,
                                              unsigned short* __restrict__ agg1b) {
    int e = blockIdx.y;
    int t = threadIdx.x;
    int lane = t & 15;
    int n = blockIdx.x * 16 + (t >> 4);
    int idx = e * N_NODES + n;
    int st = noff[idx];
    int cnt = degn[idx];
    ushort2 sv = *(const ushort2*)&fb32[n * FPAD + lane * 2];   // self term
    float a0 = bf2f(sv.x), a1 = bf2f(sv.y);
    int k = 0;
    for (; k + 3 < cnt; k += 4) {
        int s0 = csr[st + k];
        int s1 = csr[st + k + 1];
        int s2 = csr[st + k + 2];
        int s3 = csr[st + k + 3];
        ushort2 v0 = *(const ushort2*)&fb32[s0 * FPAD + lane * 2];
        ushort2 v1 = *(const ushort2*)&fb32[s1 * FPAD + lane * 2];
        ushort2 v2 = *(const ushort2*)&fb32[s2 * FPAD + lane * 2];
        ushort2 v3 = *(const ushort2*)&fb32[s3 * FPAD + lane * 2];
        a0 += bf2f(v0.x) + bf2f(v1.x) + bf2f(v2.x) + bf2f(v3.x);
        a1 += bf2f(v0.y) + bf2f(v1.y) + bf2f(v2.y) + bf2f(v3.y);
    }
    for (; k < cnt; k++) {
        int s0 = csr[st + k];
        ushort2 v0 = *(const ushort2*)&fb32[s0 * FPAD + lane * 2];
        a0 += bf2f(v0.x);
        a1 += bf2f(v0.y);
    }
    float iv = inv[idx];
    ushort2 o; o.x = f2bf(a0 * iv); o.y = f2bf(a1 * iv);
    *(ushort2*)&agg1b[(size_t)idx * 32 + lane * 2] = o;
}

// ---------------- layer1 GEMM (MFMA bf16): H1 = relu(sum_e AGG1B_e @ W1_e + B1) ---
__global__ __launch_bounds__(256) void gemm1_k(const unsigned short* __restrict__ agg1b,
                                               const unsigned short* __restrict__ w1tb,
                                               const float* __restrict__ b1s,
                                               unsigned short* __restrict__ h1b) {
    __shared__ unsigned short As[64 * A1STR];
    __shared__ unsigned short Wt[128 * A1STR];
    int t = threadIdx.x;
    int node0 = blockIdx.x * 64;
    int w = t >> 6, lane = t & 63;
    int m = lane & 15, quad = lane >> 4;

    f32x4 acc[8];
    for (int nt = 0; nt < 8; nt++) {
        float bb = b1s[nt * 16 + m];
        f32x4 c = {bb, bb, bb, bb};
        acc[nt] = c;
    }
    for (int e = 0; e < N_ETYPES; e++) {
        __syncthreads();
        for (int j = t; j < 64 * 8; j += 256) {
            int n = j >> 3, c4 = (j & 7) * 4;
            int gn = node0 + n;
            int cn = gn < N_NODES ? gn : N_NODES - 1;
            *(ushort4*)&As[n * A1STR + c4] =
                *(const ushort4*)&agg1b[(size_t)(e * N_NODES + cn) * 32 + c4];
        }
        for (int j = t; j < 128 * 8; j += 256) {
            int n = j >> 3, c4 = (j & 7) * 4;
            *(ushort4*)&Wt[n * A1STR + c4] =
                *(const ushort4*)&w1tb[(size_t)(e * HID_DIM + n) * 32 + c4];
        }
        __syncthreads();
        bf16x8 a = *(const bf16x8*)&As[(w * 16 + m) * A1STR + quad * 8];
        for (int nt = 0; nt < 8; nt++) {
            bf16x8 b = *(const bf16x8*)&Wt[(nt * 16 + m) * A1STR + quad * 8];
            acc[nt] = __builtin_amdgcn_mfma_f32_16x16x32_bf16(a, b, acc[nt], 0, 0, 0);
        }
    }
    for (int nt = 0; nt < 8; nt++) {
        for (int r = 0; r < 4; r++) {
            int gn = node0 + w * 16 + quad * 4 + r;
            if (gn < N_NODES)
                h1b[(size_t)gn * HID_DIM + nt * 16 + m] = f2bf(fmaxf(acc[nt][r], 0.f));
        }
    }
}

// ---------------- spool: M[e][g][:] += sum over src records of w * H1[src][:] -----
// grid (98, N_ETYPES): block covers 4 src-buckets (1024 nodes, 256 KB L2-hot window).
// Per bucket: counting-sort records by graph in LDS; wave w accumulates graphs
// w*16..w*16+15 in registers (2 dims/lane); one fp32 atomic flush per (g,dim).
__global__ __launch_bounds__(256) void spool_k(const int* __restrict__ offp,
                                               const unsigned* __restrict__ ep,
                                               const unsigned short* __restrict__ h1b,
                                               float* __restrict__ M) {
    __shared__ unsigned recs[BKT_CAP];
    __shared__ unsigned srt[BKT_CAP];
    __shared__ int hist[64];
    __shared__ int boff[65];
    __shared__ int curs[64];
    int q = blockIdx.x, e = blockIdx.y, t = threadIdx.x;
    int w = t >> 6, lane = t & 63;
    float a0[16], a1[16];
    #pragma unroll
    for (int gi = 0; gi < 16; gi++) { a0[gi] = 0.f; a1[gi] = 0.f; }

    for (int bi = 0; bi < 4; bi++) {
        int b = q * 4 + bi;
        if (b >= NBKT) break;
        int lin = PN + (e * NBKT + b) * PBLK;
        int S = offp[lin];
        int E = (lin + PBLK == PN2TOT) ? TOT2 : offp[lin + PBLK];
        int cnt = E - S;
        if (cnt > BKT_CAP) cnt = BKT_CAP;      // statistically never
        if (t < 64) hist[t] = 0;
        __syncthreads();
        for (int i = t; i < cnt; i += 256) {
            unsigned r = ep[S + i];
            recs[i] = r;
            atomicAdd(&hist[(r >> 16) & 63], 1);
        }
        __syncthreads();
        if (t == 0) {
            int run = 0;
            for (int g = 0; g < 64; g++) { boff[g] = run; run += hist[g]; }
            boff[64] = run;
        }
        __syncthreads();
        if (t < 64) curs[t] = boff[t];
        __syncthreads();
        for (int i = t; i < cnt; i += 256) {
            unsigned r = recs[i];
            int pos = atomicAdd(&curs[(r >> 16) & 63], 1);
            srt[pos] = r;
        }
        __syncthreads();
        int nodebase = b * 256;
        #pragma unroll
        for (int gi = 0; gi < 16; gi++) {
            int g = w * 16 + gi;
            int lo = boff[g], hi = boff[g + 1];
            int i = lo;
            for (; i + 3 < hi; i += 4) {
                unsigned r0 = srt[i], r1 = srt[i + 1], r2 = srt[i + 2], r3 = srt[i + 3];
                float w0 = bf2f((unsigned short)(r0 & 0xFFFF));
                float w1 = bf2f((unsigned short)(r1 & 0xFFFF));
                float w2 = bf2f((unsigned short)(r2 & 0xFFFF));
                float w3 = bf2f((unsigned short)(r3 & 0xFFFF));
                ushort2 v0 = *(const ushort2*)&h1b[(size_t)(nodebase + (r0 >> 24)) * HID_DIM + lane * 2];
                ushort2 v1 = *(const ushort2*)&h1b[(size_t)(nodebase + (r1 >> 24)) * HID_DIM + lane * 2];
                ushort2 v2 = *(const ushort2*)&h1b[(size_t)(nodebase + (r2 >> 24)) * HID_DIM + lane * 2];
                ushort2 v3 = *(const ushort2*)&h1b[(size_t)(nodebase + (r3 >> 24)) * HID_DIM + lane * 2];
                a0[gi] += w0 * bf2f(v0.x) + w1 * bf2f(v1.x)
                        + w2 * bf2f(v2.x) + w3 * bf2f(v3.x);
                a1[gi] += w0 * bf2f(v0.y) + w1 * bf2f(v1.y)
                        + w2 * bf2f(v2.y) + w3 * bf2f(v3.y);
            }
            for (; i < hi; i++) {
                unsigned r0 = srt[i];
                float w0 = bf2f((unsigned short)(r0 & 0xFFFF));
                ushort2 v0 = *(const ushort2*)&h1b[(size_t)(nodebase + (r0 >> 24)) * HID_DIM + lane * 2];
                a0[gi] += w0 * bf2f(v0.x);
                a1[gi] += w0 * bf2f(v0.y);
            }
        }
        __syncthreads();
    }
    #pragma unroll
    for (int gi = 0; gi < 16; gi++) {
        int g = w * 16 + gi;
        atomicAdd(&M[((size_t)e * 64 + g) * HID_DIM + lane * 2 + 0], a0[gi]);
        atomicAdd(&M[((size_t)e * 64 + g) * HID_DIM + lane * 2 + 1], a1[gi]);
    }
}

// ---------------- per-graph node counts ----------------
__global__ __launch_bounds__(256) void gcnt_k(const int* __restrict__ gid,
                                              float* __restrict__ gcnt) {
    __shared__ int h[NUM_GRAPHS];
    int b = blockIdx.x, t = threadIdx.x;
    if (t < NUM_GRAPHS) h[t] = 0;
    __syncthreads();
    int n = b * 256 + t;
    if (n < N_NODES) atomicAdd(&h[gid[n]], 1);
    __syncthreads();
    if (t < NUM_GRAPHS && h[t] > 0) atomicAdd(&gcnt[t], (float)h[t]);
}

// ---------------- final: OUT[g] = (sum_e M[e][g] @ W2_e + cnt_g*B2) / cnt_g ------
__global__ __launch_bounds__(64) void final2_k(const float* __restrict__ M,
                                               const float* __restrict__ W2,
                                               const float* __restrict__ b2,
                                               const float* __restrict__ gcnt,
                                               float* __restrict__ out) {
    int g = blockIdx.x, d = threadIdx.x;
    float s = 0.f;
    for (int e = 0; e < N_ETYPES; e++) {
        const float* mrow = M + ((size_t)e * 64 + g) * HID_DIM;
        const float* wmat = W2 + (size_t)e * HID_DIM * OUT_DIM;
        for (int k = 0; k < HID_DIM; k++)
            s += mrow[k] * wmat[k * OUT_DIM + d];
    }
    float B2 = 0.f;
    for (int e = 0; e < N_ETYPES; e++) B2 += b2[e * OUT_DIM + d];
    float c = gcnt[g];
    out[g * OUT_DIM + d] = (s + c * B2) / fmaxf(c, 1.0f);
}

extern "C" void kernel_launch(void* const* d_in, const int* in_sizes, int n_in,
                              void* d_out, int out_size, void* d_ws, size_t ws_size,
                              hipStream_t stream) {
    const float* feat = (const float*)d_in[0];
    const int*   src  = (const int*)d_in[1];
    const int*   dst  = (const int*)d_in[2];
    const int*   gid  = (const int*)d_in[3];
    const float* W1   = (const float*)d_in[4];
    const float* b1   = (const float*)d_in[5];
    const float* W2   = (const float*)d_in[6];
    const float* b2   = (const float*)d_in[7];

    float* ws = (float*)d_ws;
    int*            HP   = (int*)ws;                         //   488,750 (pad 490,000)
    int*            OFFP = (int*)ws + 490000;                //   488,750 (pad 490,000)
    int*            BSUM = (int*)ws + 980000;                //   512
    float*          INV  = ws + 980512;                      //   500,000
    int*            NOFF = (int*)ws + 1480512;               //   500,000
    int*            DEGN = (int*)ws + 1980512;               //   500,000
    unsigned short* FB32 = (unsigned short*)(ws + 2480512);  //   3.2M bf16 = 1,600,000 f
    float*          Mbuf = ws + 4080512;                     //   40,960
    float*          GCNT = ws + 4121472;                     //   64
    unsigned*       EP   = (unsigned*)(ws + 4121600);        //   8,500,000 (dst+src recs)
    unsigned*       CSR  = (unsigned*)(ws + 12621600);       //   4,000,000
    unsigned short* AGG1B= (unsigned short*)(ws + 16621600); //  16M bf16 = 8,000,000 f
    unsigned short* H1B  = (unsigned short*)(ws + 24621600); //  12.8M bf16 = 6,400,000 f
    unsigned short* W1TB = (unsigned short*)(ws + 31021600); //  20,480 bf16 = 10,240 f
    float*          B1S  = ws + 31031840;                    //   128
    // total 31,031,968 floats = 124.1 MB

    hipMemsetAsync(Mbuf, 0, (size_t)(40960 + 64 + 64) * sizeof(float), stream); // M+GCNT

    cvt_feat_k<<<(N_NODES * FPAD + 255) / 256, 256, 0, stream>>>(feat, FB32);
    cvt_w_k<<<(N_ETYPES * HID_DIM * 32 + 255) / 256, 256, 0, stream>>>(W1, b1, W1TB, B1S);
    part1_k<<<dim3(PBLK, N_ETYPES), 256, 0, stream>>>(src, dst, HP);
    scan1_k<<<SCAN_NBLK, 256, 0, stream>>>(HP, OFFP, BSUM);
    scan2_k<<<1, 512, 0, stream>>>(BSUM);
    scan3_k<<<(PN2TOT + 255) / 256, 256, 0, stream>>>(OFFP, BSUM);
    part2_k<<<dim3(PBLK, N_ETYPES), 256, 0, stream>>>(src, dst, OFFP, EP);
    sort_k<<<dim3(NBKT, N_ETYPES), 256, 0, stream>>>(OFFP, EP, CSR, NOFF, DEGN, INV);
    part2b_k<<<dim3(PBLK, N_ETYPES), 256, 0, stream>>>(src, dst, gid, INV, OFFP, EP);

    agg1_k<<<dim3(6250, N_ETYPES), 256, 0, stream>>>(NOFF, DEGN, CSR, FB32, INV, AGG1B);
    gemm1_k<<<(N_NODES + 63) / 64, 256, 0, stream>>>(AGG1B, W1TB, B1S, H1B);
    spool_k<<<dim3(98, N_ETYPES), 256, 0, stream>>>(OFFP, EP, H1B, Mbuf);

    gcnt_k<<<391, 256, 0, stream>>>(gid, GCNT);
    final2_k<<<NUM_GRAPHS, 64, 0, stream>>>(Mbuf, W2, b2, GCNT, (float*)d_out);
}

// Round 13
// 385.670 us; speedup vs baseline: 1.8043x; 1.8043x over previous
//
#include <hip/hip_runtime.h>

#define N_NODES   100000
#define N_EDGES   800000
#define N_ETYPES  5
#define IN_DIM    23
#define HID_DIM   128
#define OUT_DIM   64
#define NUM_GRAPHS 64
#define NBKT      391                   // ceil(100000/256) dst buckets of 256 nodes
#define PBLK      125                   // partition blocks per etype
#define CHUNK     6400                  // 125*6400 = 800000 edges per etype
#define NB_E      (N_ETYPES*NBKT)       // 1955 (e,bucket) pairs
#define BKT_CAP   3072                  // slot size per (e,bucket); mean 2048 + 22 sigma
#define ASTR      136                   // gemm2-phase LDS stride: conflict-free b128 frags
#define A1STR     40                    // gemm1-phase LDS stride: 2-way only (free)

// NOTE (measured r3): bulk LDS float atomics ~3.5 cyc/lane on gfx950 — register acc only.
// NOTE (measured r6): unpadded bf16 LDS tiles -> 16-way conflicts on MFMA ds_read_b128.
// NOTE (measured r7-r11): random row-gather over a table >4MB/XCD has a compulsory
// L2-miss floor of 8 XCDs x table bytes; tuning can't reduce it. Tables <4MB/XCD
// (fp8 feat, 3.2 MB) stay L2-resident.
// NOTE (measured r12): pool-commute spool over 256 B H1 rows octupled the edge payload
// (2.2 GB) and ran at 20% occupancy — 4x regression. Pool-commute only pays if the
// spooled rows are NARROWER than the gathered rows. Reverted to dst-gather of fp8 t2.

__device__ __forceinline__ unsigned short f2bf(float x) {
    unsigned u = __float_as_uint(x);
    unsigned r = (u + 0x7FFFu + ((u >> 16) & 1u)) >> 16;   // RNE
    return (unsigned short)r;
}
__device__ __forceinline__ float bf2f(unsigned short h) {
    return __uint_as_float(((unsigned)h) << 16);
}

typedef __attribute__((ext_vector_type(8))) short bf16x8;
typedef __attribute__((ext_vector_type(4))) float f32x4;
typedef __attribute__((ext_vector_type(2))) float f32x2;

// ---------------- feat -> fp8-e4m3 table, 32-dim rows (32 B, table 3.2 MB) -------
__global__ __launch_bounds__(256) void cvt_feat_k(const float* __restrict__ feat,
                                                  unsigned short* __restrict__ fb8) {
    int i = blockIdx.x * 256 + threadIdx.x;
    if (i < N_NODES * 16) {
        int n = i >> 4, p = i & 15;
        int d0 = p * 2, d1 = d0 + 1;
        float f0 = (d0 < IN_DIM) ? feat[n * IN_DIM + d0] : 0.f;
        float f1 = (d1 < IN_DIM) ? feat[n * IN_DIM + d1] : 0.f;
        int pk = __builtin_amdgcn_cvt_pk_fp8_f32(f0, f1, 0, false);
        fb8[i] = (unsigned short)(pk & 0xFFFF);
    }
}

// ---------------- weight prep: W1^T bf16 (k-pad 32), W2^T bf16, b1 sum ----------
__global__ __launch_bounds__(256) void cvt_w_k(const float* __restrict__ W1,
                                               const float* __restrict__ b1,
                                               const float* __restrict__ W2,
                                               unsigned short* __restrict__ w1tb,
                                               unsigned short* __restrict__ w2tb,
                                               float* __restrict__ b1s) {
    int i = blockIdx.x * 256 + threadIdx.x;
    if (i < N_ETYPES * OUT_DIM * HID_DIM) {
        int e = i / (OUT_DIM * HID_DIM);
        int r = i - e * (OUT_DIM * HID_DIM);
        int n = r >> 7, k = r & 127;
        w2tb[i] = f2bf(W2[(e * HID_DIM + k) * OUT_DIM + n]);
    }
    if (i < N_ETYPES * HID_DIM * 32) {
        int e = i / (HID_DIM * 32);
        int r = i - e * (HID_DIM * 32);
        int n = r >> 5, k = r & 31;
        w1tb[i] = (k < IN_DIM) ? f2bf(W1[e * IN_DIM * HID_DIM + k * HID_DIM + n])
                               : (unsigned short)0;
    }
    if (i < HID_DIM) {
        float s = 0.f;
        for (int e = 0; e < N_ETYPES; e++) s += b1[e * HID_DIM + i];
        b1s[i] = s;
    }
}

// ---------------- fused partition: hist + atomic range-reserve + scatter ---------
// Slotted EP: bucket (e,b) owns records [lin*BKT_CAP, lin*BKT_CAP+cnt). No scan.
__global__ __launch_bounds__(256) void part_k(const int* __restrict__ src,
                                              const int* __restrict__ dst,
                                              int* __restrict__ gcur,
                                              unsigned* __restrict__ ep) {
    __shared__ int hist[NBKT];
    __shared__ int cur[NBKT];
    int e = blockIdx.y, blk = blockIdx.x, t = threadIdx.x;
    for (int b = t; b < NBKT; b += 256) hist[b] = 0;
    __syncthreads();
    const int* dp = dst + e * N_EDGES + blk * CHUNK;
    const int* sp = src + e * N_EDGES + blk * CHUNK;
    for (int k = t; k < CHUNK; k += 256) atomicAdd(&hist[dp[k] >> 8], 1);
    __syncthreads();
    for (int b = t; b < NBKT; b += 256)
        cur[b] = (hist[b] > 0) ? atomicAdd(&gcur[e * NBKT + b], hist[b]) : 0;
    __syncthreads();
    for (int k = t; k < CHUNK; k += 256) {
        int d = dp[k], s = sp[k];
        int b = d >> 8;
        int pos = atomicAdd(&cur[b], 1);
        if (pos < BKT_CAP)
            ep[(size_t)(e * NBKT + b) * BKT_CAP + pos] =
                (unsigned)s | ((unsigned)(d & 255) << 24);
    }
}

// ---------------- per-bucket counting sort -> node-sorted CSR + NOFF/DEG/INV ---
__global__ __launch_bounds__(256) void sort_k(const int* __restrict__ gcur,
                                              const unsigned* __restrict__ ep,
                                              unsigned* __restrict__ csr,
                                              int* __restrict__ noff,
                                              int* __restrict__ degn,
                                              float* __restrict__ inv) {
    __shared__ unsigned recs[BKT_CAP];
    __shared__ int hist[256];
    __shared__ int scn[256];
    __shared__ int curp[256];
    int b = blockIdx.x, e = blockIdx.y, t = threadIdx.x;
    int lin = e * NBKT + b;
    int S = lin * BKT_CAP;
    int cnt = gcur[lin];
    if (cnt > BKT_CAP) cnt = BKT_CAP;
    hist[t] = 0;
    __syncthreads();
    for (int i = t; i < cnt; i += 256) {
        unsigned r = ep[S + i];
        recs[i] = r;
        atomicAdd(&hist[r >> 24], 1);
    }
    __syncthreads();
    scn[t] = hist[t];
    __syncthreads();
    for (int o = 1; o < 256; o <<= 1) {
        int x = (t >= o) ? scn[t - o] : 0;
        __syncthreads();
        scn[t] += x;
        __syncthreads();
    }
    int excl = scn[t] - hist[t];
    curp[t] = excl;
    int n = b * 256 + t;
    if (n < N_NODES) {
        noff[e * N_NODES + n] = S + excl;
        degn[e * N_NODES + n] = hist[t];
        inv[e * N_NODES + n]  = 1.f / (float)(hist[t] + 1);
    }
    __syncthreads();
    for (int i = t; i < cnt; i += 256) {
        unsigned r = recs[i];
        int pos = atomicAdd(&curp[r >> 24], 1);
        csr[S + pos] = r & 0xFFFFFFu;
    }
}

// ---------------- layer1 pull-aggregate over fp8 feat (L2-resident table) --------
// AGG1B[e,n,0:32] = bf16( inv * (sum_{j->n} fp8feat[j] + fp8feat[n]) ).
// 16 lanes x ushort (2 fp8) per node; unroll-4.
__global__ __launch_bounds__(256) void agg1_k(const int* __restrict__ noff,
                                              const int* __restrict__ degn,
                                              const unsigned* __restrict__ csr,
                                              const unsigned short* __restrict__ fb8,
                                              const float* __restrict__ inv,
                                              unsigned short* __restrict__ agg1b) {
    int e = blockIdx.y;
    int t = threadIdx.x;
    int lane = t & 15;
    int n = blockIdx.x * 16 + (t >> 4);
    int idx = e * N_NODES + n;
    int st = noff[idx];
    int cnt = degn[idx];
    f32x2 sv = __builtin_amdgcn_cvt_pk_f32_fp8((int)fb8[n * 16 + lane], false);
    float a0 = sv.x, a1 = sv.y;
    int k = 0;
    for (; k + 3 < cnt; k += 4) {
        int s0 = csr[st + k];
        int s1 = csr[st + k + 1];
        int s2 = csr[st + k + 2];
        int s3 = csr[st + k + 3];
        unsigned short r0 = fb8[s0 * 16 + lane];
        unsigned short r1 = fb8[s1 * 16 + lane];
        unsigned short r2 = fb8[s2 * 16 + lane];
        unsigned short r3 = fb8[s3 * 16 + lane];
        f32x2 v0 = __builtin_amdgcn_cvt_pk_f32_fp8((int)r0, false);
        f32x2 v1 = __builtin_amdgcn_cvt_pk_f32_fp8((int)r1, false);
        f32x2 v2 = __builtin_amdgcn_cvt_pk_f32_fp8((int)r2, false);
        f32x2 v3 = __builtin_amdgcn_cvt_pk_f32_fp8((int)r3, false);
        a0 += (v0.x + v1.x) + (v2.x + v3.x);
        a1 += (v0.y + v1.y) + (v2.y + v3.y);
    }
    for (; k < cnt; k++) {
        int s0 = csr[st + k];
        f32x2 v0 = __builtin_amdgcn_cvt_pk_f32_fp8((int)fb8[s0 * 16 + lane], false);
        a0 += v0.x;
        a1 += v0.y;
    }
    float iv = inv[idx];
    ushort2 o; o.x = f2bf(a0 * iv); o.y = f2bf(a1 * iv);
    *(ushort2*)&agg1b[(size_t)idx * 32 + lane * 2] = o;
}

// ---------------- fused MLP (MFMA bf16): H1 in LDS, t2f8_e = fp8(H1 @ W2_e) ------
__global__ __launch_bounds__(256) void gemm12_k(const unsigned short* __restrict__ agg1b,
                                                const unsigned short* __restrict__ w1tb,
                                                const float* __restrict__ b1s,
                                                const unsigned short* __restrict__ w2tb,
                                                unsigned char* __restrict__ t2f8) {
    __shared__ unsigned short H1s[64 * ASTR];   // 17.4 KB [node][k]
    __shared__ unsigned short Wt2[64 * ASTR];   // 17.4 KB; phase1 aliases:
    unsigned short* As1 = Wt2;                  //   [64*A1STR]  = 2560 ushorts
    unsigned short* Wt1 = Wt2 + 64 * A1STR;     //   [128*A1STR] = 5120 (7680 <= 8704 ok)
    int t = threadIdx.x;
    int node0 = blockIdx.x * 64;
    int w = t >> 6, lane = t & 63;
    int m = lane & 15, quad = lane >> 4;

    // ---- phase 1: H1 = relu(sum_e A_e @ W1_e + b1s)
    f32x4 acc[8];
    for (int nt = 0; nt < 8; nt++) {
        float bb = b1s[nt * 16 + m];
        f32x4 c = {bb, bb, bb, bb};
        acc[nt] = c;
    }
    for (int e = 0; e < N_ETYPES; e++) {
        __syncthreads();
        for (int j = t; j < 64 * 8; j += 256) {
            int n = j >> 3, c4 = (j & 7) * 4;
            int gn = node0 + n;
            int cn = gn < N_NODES ? gn : N_NODES - 1;
            *(ushort4*)&As1[n * A1STR + c4] =
                *(const ushort4*)&agg1b[(size_t)(e * N_NODES + cn) * 32 + c4];
        }
        for (int j = t; j < 128 * 8; j += 256) {
            int n = j >> 3, c4 = (j & 7) * 4;
            *(ushort4*)&Wt1[n * A1STR + c4] =
                *(const ushort4*)&w1tb[(size_t)(e * HID_DIM + n) * 32 + c4];
        }
        __syncthreads();
        bf16x8 a = *(const bf16x8*)&As1[(w * 16 + m) * A1STR + quad * 8];
        for (int nt = 0; nt < 8; nt++) {
            bf16x8 b = *(const bf16x8*)&Wt1[(nt * 16 + m) * A1STR + quad * 8];
            acc[nt] = __builtin_amdgcn_mfma_f32_16x16x32_bf16(a, b, acc[nt], 0, 0, 0);
        }
    }
    __syncthreads();                           // done reading As1/Wt1 (aliases Wt2)
    for (int nt = 0; nt < 8; nt++)
        for (int r = 0; r < 4; r++)
            H1s[(w * 16 + quad * 4 + r) * ASTR + nt * 16 + m] =
                f2bf(fmaxf(acc[nt][r], 0.f));
    __syncthreads();

    // ---- phase 2: t2_e = fp8(H1 @ W2_e)
    bf16x8 a2[4];
    for (int ks = 0; ks < 4; ks++)
        a2[ks] = *(const bf16x8*)&H1s[(w * 16 + m) * ASTR + ks * 32 + quad * 8];
    for (int e = 0; e < N_ETYPES; e++) {
        __syncthreads();                       // protect Wt2 from prev readers
        for (int j = t; j < 64 * 32; j += 256) {
            int n = j >> 5, c4 = (j & 31) * 4;
            *(ushort4*)&Wt2[n * ASTR + c4] =
                *(const ushort4*)&w2tb[(e * OUT_DIM + n) * HID_DIM + c4];
        }
        __syncthreads();
        unsigned char* out = t2f8 + (size_t)e * N_NODES * OUT_DIM;
        for (int nt = 0; nt < 4; nt++) {
            f32x4 c = {0.f, 0.f, 0.f, 0.f};
            for (int ks = 0; ks < 4; ks++) {
                bf16x8 b = *(const bf16x8*)&Wt2[(nt * 16 + m) * ASTR + ks * 32 + quad * 8];
                c = __builtin_amdgcn_mfma_f32_16x16x32_bf16(a2[ks], b, c, 0, 0, 0);
            }
            for (int r = 0; r < 4; r++) {
                int gn = node0 + w * 16 + quad * 4 + r;
                if (gn < N_NODES) {
                    int p = __builtin_amdgcn_cvt_pk_fp8_f32(c[r], c[r], 0, false);
                    out[(size_t)gn * OUT_DIM + nt * 16 + m] = (unsigned char)(p & 0xFF);
                }
            }
        }
    }
}

// ---------------- layer2 pull + per-graph pool (r10-measured-best form) ----------
// grid (NBKT, 8): block = 32 nodes; 16 lanes x uint (4 fp8); etype-outer; unroll-4.
__global__ __launch_bounds__(256) void gather2_k(const int* __restrict__ noff,
                                                 const int* __restrict__ degn,
                                                 const float* __restrict__ inv,
                                                 const unsigned* __restrict__ csr,
                                                 const unsigned char* __restrict__ t2f8,
                                                 const int* __restrict__ gid,
                                                 float* __restrict__ gsum) {
    __shared__ float4 red4[16 * 4 * 16];    // 16 KB: [ng][slot][lane]
    int b = blockIdx.x, qb = blockIdx.y, t = threadIdx.x;
    int lane = t & 15, ng = t >> 4;
    int nbase = b * 256 + qb * 32;
    int gbase = nbase < N_NODES ? nbase : N_NODES - 1;
    int g0 = gid[gbase];
    float4 f[2];
    f[0] = make_float4(0.f, 0.f, 0.f, 0.f);
    f[1] = make_float4(0.f, 0.f, 0.f, 0.f);

    for (int e = 0; e < N_ETYPES; e++) {
        const unsigned char* base = t2f8 + (size_t)e * N_NODES * OUT_DIM;
        #pragma unroll
        for (int pass = 0; pass < 2; pass++) {
            int n = nbase + pass * 16 + ng;
            if (n >= N_NODES) break;
            int idx = e * N_NODES + n;
            int st = noff[idx];
            int cnt = degn[idx];
            float iv = inv[idx];
            unsigned rv = *(const unsigned*)&base[(size_t)n * OUT_DIM + lane * 4];
            f32x2 lo = __builtin_amdgcn_cvt_pk_f32_fp8((int)rv, false);
            f32x2 hi = __builtin_amdgcn_cvt_pk_f32_fp8((int)rv, true);
            float ax = lo.x, ay = lo.y, az = hi.x, aw = hi.y;
            int k = 0;
            for (; k + 3 < cnt; k += 4) {
                int sA = csr[st + k];
                int sB = csr[st + k + 1];
                int sC = csr[st + k + 2];
                int sD = csr[st + k + 3];
                unsigned rA = *(const unsigned*)&base[(size_t)sA * OUT_DIM + lane * 4];
                unsigned rB = *(const unsigned*)&base[(size_t)sB * OUT_DIM + lane * 4];
                unsigned rC = *(const unsigned*)&base[(size_t)sC * OUT_DIM + lane * 4];
                unsigned rD = *(const unsigned*)&base[(size_t)sD * OUT_DIM + lane * 4];
                f32x2 lA = __builtin_amdgcn_cvt_pk_f32_fp8((int)rA, false);
                f32x2 hA = __builtin_amdgcn_cvt_pk_f32_fp8((int)rA, true);
                f32x2 lB = __builtin_amdgcn_cvt_pk_f32_fp8((int)rB, false);
                f32x2 hB = __builtin_amdgcn_cvt_pk_f32_fp8((int)rB, true);
                f32x2 lC = __builtin_amdgcn_cvt_pk_f32_fp8((int)rC, false);
                f32x2 hC = __builtin_amdgcn_cvt_pk_f32_fp8((int)rC, true);
                f32x2 lD = __builtin_amdgcn_cvt_pk_f32_fp8((int)rD, false);
                f32x2 hD = __builtin_amdgcn_cvt_pk_f32_fp8((int)rD, true);
                ax += (lA.x + lB.x) + (lC.x + lD.x);
                ay += (lA.y + lB.y) + (lC.y + lD.y);
                az += (hA.x + hB.x) + (hC.x + hD.x);
                aw += (hA.y + hB.y) + (hC.y + hD.y);
            }
            for (; k < cnt; k++) {
                int sA = csr[st + k];
                unsigned rA = *(const unsigned*)&base[(size_t)sA * OUT_DIM + lane * 4];
                f32x2 lA = __builtin_amdgcn_cvt_pk_f32_fp8((int)rA, false);
                f32x2 hA = __builtin_amdgcn_cvt_pk_f32_fp8((int)rA, true);
                ax += lA.x; ay += lA.y; az += hA.x; aw += hA.y;
            }
            f[pass].x += iv * ax; f[pass].y += iv * ay;
            f[pass].z += iv * az; f[pass].w += iv * aw;
        }
    }

    float4 sa0 = {0,0,0,0}, sa1 = {0,0,0,0}, sa2 = {0,0,0,0}, sa3 = {0,0,0,0};
    #pragma unroll
    for (int pass = 0; pass < 2; pass++) {
        int n = nbase + pass * 16 + ng;
        if (n >= N_NODES) break;
        float4 v = f[pass];
        int slot = gid[n] - g0;
        float m0 = (slot == 0) ? 1.f : 0.f;
        float m1 = (slot == 1) ? 1.f : 0.f;
        float m2 = (slot == 2) ? 1.f : 0.f;
        float m3 = (slot == 3) ? 1.f : 0.f;
        sa0.x += m0 * v.x; sa0.y += m0 * v.y; sa0.z += m0 * v.z; sa0.w += m0 * v.w;
        sa1.x += m1 * v.x; sa1.y += m1 * v.y; sa1.z += m1 * v.z; sa1.w += m1 * v.w;
        sa2.x += m2 * v.x; sa2.y += m2 * v.y; sa2.z += m2 * v.z; sa2.w += m2 * v.w;
        sa3.x += m3 * v.x; sa3.y += m3 * v.y; sa3.z += m3 * v.z; sa3.w += m3 * v.w;
        if (slot > 3) {                      // statistically never
            atomicAdd(&gsum[(g0 + slot) * 64 + lane * 4 + 0], v.x);
            atomicAdd(&gsum[(g0 + slot) * 64 + lane * 4 + 1], v.y);
            atomicAdd(&gsum[(g0 + slot) * 64 + lane * 4 + 2], v.z);
            atomicAdd(&gsum[(g0 + slot) * 64 + lane * 4 + 3], v.w);
        }
    }
    red4[(ng * 4 + 0) * 16 + lane] = sa0;
    red4[(ng * 4 + 1) * 16 + lane] = sa1;
    red4[(ng * 4 + 2) * 16 + lane] = sa2;
    red4[(ng * 4 + 3) * 16 + lane] = sa3;
    __syncthreads();
    const float* red = (const float*)red4;
    int slot = t >> 6, d = t & 63;
    float s = 0.f;
    for (int j = 0; j < 16; j++) s += red[(j * 4 + slot) * 64 + d];
    int g = g0 + slot;
    if (g < NUM_GRAPHS) atomicAdd(&gsum[g * 64 + d], s);
}

// ---------------- per-graph node counts ----------------
__global__ __launch_bounds__(256) void gcnt_k(const int* __restrict__ gid,
                                              float* __restrict__ gcnt) {
    __shared__ int h[NUM_GRAPHS];
    int b = blockIdx.x, t = threadIdx.x;
    if (t < NUM_GRAPHS) h[t] = 0;
    __syncthreads();
    int n = b * 256 + t;
    if (n < N_NODES) atomicAdd(&h[gid[n]], 1);
    __syncthreads();
    if (t < NUM_GRAPHS && h[t] > 0) atomicAdd(&gcnt[t], (float)h[t]);
}

__global__ __launch_bounds__(256) void final_k(const float* __restrict__ gsum,
                                               const float* __restrict__ gcnt,
                                               const float* __restrict__ b2,
                                               float* __restrict__ out) {
    int idx = blockIdx.x * 256 + threadIdx.x;
    if (idx >= NUM_GRAPHS * OUT_DIM) return;
    int d = idx & 63;
    float B2 = 0.f;
    for (int e = 0; e < N_ETYPES; e++) B2 += b2[e * OUT_DIM + d];
    float c = gcnt[idx >> 6];
    out[idx] = (gsum[idx] + c * B2) / fmaxf(c, 1.0f);
}

extern "C" void kernel_launch(void* const* d_in, const int* in_sizes, int n_in,
                              void* d_out, int out_size, void* d_ws, size_t ws_size,
                              hipStream_t stream) {
    const float* feat = (const float*)d_in[0];
    const int*   src  = (const int*)d_in[1];
    const int*   dst  = (const int*)d_in[2];
    const int*   gid  = (const int*)d_in[3];
    const float* W1   = (const float*)d_in[4];
    const float* b1   = (const float*)d_in[5];
    const float* W2   = (const float*)d_in[6];
    const float* b2   = (const float*)d_in[7];

    float* ws = (float*)d_ws;
    int*            GCUR = (int*)ws;                         //   1,955 (pad 2,048)
    float*          INV  = ws + 2048;                        //   500,000
    int*            NOFF = (int*)ws + 502048;                //   500,000
    int*            DEGN = (int*)ws + 1002048;               //   500,000
    unsigned short* FB8  = (unsigned short*)(ws + 1502048);  //   1.6M ushort = 800,000 f
    float*          GSUM = ws + 2302048;                     //   4,096
    float*          GCNT = ws + 2306144;                     //   64
    unsigned*       EP   = (unsigned*)(ws + 2306208);        //   6,005,760 (slotted)
    unsigned*       CSR  = (unsigned*)(ws + 8311968);        //   6,005,760 (slotted)
    unsigned short* AGG1B= (unsigned short*)(ws + 14317728); //  16M bf16 = 8,000,000 f
    unsigned char*  T2F8 = (unsigned char*)(ws + 22317728);  //  32 MB = 8,000,000 f
    unsigned short* W1TB = (unsigned short*)(ws + 30317728); //  20,480 bf16 = 10,240 f
    unsigned short* W2TB = (unsigned short*)(ws + 30327968); //  40,960 bf16 = 20,480 f
    float*          B1S  = ws + 30348448;                    //   128
    // total 30,348,576 floats = 121.4 MB

    hipMemsetAsync(GCUR, 0, 2048 * sizeof(int), stream);
    hipMemsetAsync(GSUM, 0, (size_t)(4096 + 64) * sizeof(float), stream);

    cvt_feat_k<<<(N_NODES * 16 + 255) / 256, 256, 0, stream>>>(feat, FB8);
    cvt_w_k<<<(N_ETYPES * OUT_DIM * HID_DIM + 255) / 256, 256, 0, stream>>>(
        W1, b1, W2, W1TB, W2TB, B1S);
    part_k<<<dim3(PBLK, N_ETYPES), 256, 0, stream>>>(src, dst, GCUR, EP);
    sort_k<<<dim3(NBKT, N_ETYPES), 256, 0, stream>>>(GCUR, EP, CSR, NOFF, DEGN, INV);

    agg1_k<<<dim3(6250, N_ETYPES), 256, 0, stream>>>(NOFF, DEGN, CSR, FB8, INV, AGG1B);
    gemm12_k<<<(N_NODES + 63) / 64, 256, 0, stream>>>(AGG1B, W1TB, B1S, W2TB, T2F8);
    gather2_k<<<dim3(NBKT, 8), 256, 0, stream>>>(NOFF, DEGN, INV, CSR, T2F8, gid, GSUM);

    gcnt_k<<<391, 256, 0, stream>>>(gid, GCNT);
    final_k<<<16, 256, 0, stream>>>(GSUM, GCNT, b2, (float*)d_out);
}